// Round 11
// baseline (718.526 us; speedup 1.0000x reference)
//
#include <hip/hip_runtime.h>

#define D 64
#define S0 10           // learner-side bucket shift (1024 rows/bucket)
#define BCHUNK 8        // edges per thread in bin pass
#define EPB (256 * BCHUNK)

__device__ __forceinline__ unsigned int f2bf(float x) {
  unsigned int u = __float_as_uint(x);
  return (u + 0x7FFFu + ((u >> 16) & 1u)) >> 16;
}

// ============================ params ============================

struct BP {
  const int *cgr, *cgc, *kgr, *kgc, *car;
  long long EcgH, EkgH, Eca, Ecg, Ekg;
  int Bcg, Bkg;
  int L, Ncg, Nkg, NB0, NBcg, NBkg, s1cg, s1kg;
  int capcg0, capcg1, capkg0, capkg1;
  long long padcg;
  int *gcur;            // [512] padded-region cursors (cg 0..255, kg 256..511)
  int *bkt;             // [512] bucket CSR bases (cg 0..255, kg 256..511)
  int *cadeg;
  int *binned;          // padded bucket regions
  int *rp0, *rp1, *cv0, *cv1;
  float *scal;          // cg at [0], kg at [Ncg]
  unsigned short *g0;   // cg rows [0,Ncg), kg rows [Ncg,Ncg+Nkg)
  const float *learners, *courses, *concepts;
};

__device__ __forceinline__ long long rbase(const BP& P, int g, int b) {
  if (g == 0)
    return b < P.NB0 ? (long long)b * P.capcg0
                     : (long long)P.NB0 * P.capcg0 + (long long)(b - P.NB0) * P.capcg1;
  return P.padcg + (b < P.NB0 ? (long long)b * P.capkg0
                              : (long long)P.NB0 * P.capkg0 + (long long)(b - P.NB0) * P.capkg1);
}

// ============================ element-wise utils (fallback only) ============================

__global__ __launch_bounds__(256) void axcopy_kernel(float* __restrict__ dst,
                                                     const float* __restrict__ src,
                                                     long long n4, float s) {
  long long i = (long long)blockIdx.x * blockDim.x + threadIdx.x;
  long long stride = (long long)gridDim.x * blockDim.x;
  for (; i < n4; i += stride) {
    float4 v = ((const float4*)src)[i];
    v.x *= s; v.y *= s; v.z *= s; v.w *= s;
    ((float4*)dst)[i] = v;
  }
}

// ============================ build ============================

// init padded-region cursors to region bases
__global__ __launch_bounds__(512) void init_gcur_kernel(BP P) {
  int t = threadIdx.x;
  if (t < 256) {
    if (t < P.NBcg) P.gcur[t] = (int)rbase(P, 0, t);
  } else {
    int b = t - 256;
    if (b < P.NBkg) P.gcur[256 + b] = (int)rbase(P, 1, b);
  }
}

// One dispatch: cg binning | kg binning | ca degree count.
// Bin path: LDS per-bucket counts, one global atomicAdd per (block,bucket) to
// reserve a contiguous slot range in the bucket's padded region, then write
// packed entries (rowInBucket<<17 | col) for both sides of each half-COO edge.
__global__ __launch_bounds__(256) void binD_all_kernel(BP P) {
  int B = blockIdx.x;
  int t = threadIdx.x;
  if (B >= P.Bcg + P.Bkg) {
    long long base = (long long)(B - P.Bcg - P.Bkg) * EPB;
    #pragma unroll
    for (int k = 0; k < BCHUNK; k++) {
      long long i = base + (long long)k * 256 + t;
      if (i < P.Eca) atomicAdd(&P.cadeg[P.car[i]], 1);
    }
    return;
  }
  const int* rowsA; const int* colsA; long long E; int s1, NBtot, goff; long long eb;
  if (B < P.Bcg) { rowsA = P.cgr; colsA = P.cgc; E = P.EcgH; s1 = P.s1cg; NBtot = P.NBcg; goff = 0;   eb = (long long)B * EPB; }
  else           { rowsA = P.kgr; colsA = P.kgc; E = P.EkgH; s1 = P.s1kg; NBtot = P.NBkg; goff = 256; eb = (long long)(B - P.Bcg) * EPB; }

  __shared__ int cnt[256];
  __shared__ int gbase[256];
  cnt[t] = 0;
  __syncthreads();
  int av[BCHUNK], cv_[BCHUNK], l0[BCHUNK], l1[BCHUNK];
  #pragma unroll
  for (int k = 0; k < BCHUNK; k++) {
    long long i = eb + (long long)k * 256 + t;
    bool ok = i < E;
    int a = ok ? rowsA[i] : 0;
    int c = ok ? colsA[i] : P.L;
    av[k] = a; cv_[k] = c;
    if (ok) {
      int b0 = a >> S0;
      int b1 = P.NB0 + ((c - P.L) >> s1);
      l0[k] = atomicAdd(&cnt[b0], 1);
      l1[k] = atomicAdd(&cnt[b1], 1);
    } else { l0[k] = 0; l1[k] = 0; }
  }
  __syncthreads();
  if (t < NBtot) gbase[t] = cnt[t] ? atomicAdd(&P.gcur[goff + t], cnt[t]) : 0;
  __syncthreads();
  #pragma unroll
  for (int k = 0; k < BCHUNK; k++) {
    long long i = eb + (long long)k * 256 + t;
    if (i < E) {
      int a = av[k], c = cv_[k];
      int b0 = a >> S0;
      int b1 = P.NB0 + ((c - P.L) >> s1);
      P.binned[gbase[b0] + l0[k]] = ((a & ((1 << S0) - 1)) << 17) | c;
      P.binned[gbase[b1] + l1[k]] = (((c - P.L) & ((1 << s1) - 1)) << 17) | a;
    }
  }
}

// 1-block: bucket counts (cursor - regionbase) -> exclusive scan -> CSR bases; sentinels.
__global__ __launch_bounds__(256) void scan_all_kernel(BP P) {
  __shared__ int lds[256];
  int t = threadIdx.x;
  #pragma unroll
  for (int g = 0; g < 2; ++g) {
    int NB = g ? P.NBkg : P.NBcg;
    int c = 0;
    if (t < NB) c = P.gcur[g * 256 + t] - (int)rbase(P, g, t);
    lds[t] = c;
    __syncthreads();
    for (int off = 1; off < 256; off <<= 1) {
      int x = (t >= off) ? lds[t - off] : 0;
      __syncthreads();
      lds[t] += x;
      __syncthreads();
    }
    if (t < NB) P.bkt[g * 256 + t] = (t == 0) ? 0 : lds[t - 1];
    __syncthreads();
  }
  if (t == 0) { P.rp0[P.Ncg] = (int)P.Ecg; P.rp1[P.Nkg] = (int)P.Ekg; }
}

// ca scans (rowptr + inv-degree scale + cursors), tile = 1024
__global__ __launch_bounds__(256) void ca_scan1_kernel(const int* __restrict__ deg,
                                                       int* __restrict__ rp,
                                                       float* __restrict__ scal,
                                                       int* __restrict__ part, int n) {
  __shared__ int lds[256];
  int b = blockIdx.x, t = threadIdx.x;
  int base = b * 1024 + t * 4;
  int v[4]; int s = 0;
  #pragma unroll
  for (int j = 0; j < 4; j++) {
    int idx = base + j;
    v[j] = (idx < n) ? deg[idx] : 0;
    if (idx < n) scal[idx] = 1.0f / ((float)v[j] + 1e-8f);
    s += v[j];
  }
  lds[t] = s;
  __syncthreads();
  for (int off = 1; off < 256; off <<= 1) {
    int x = (t >= off) ? lds[t - off] : 0;
    __syncthreads();
    lds[t] += x;
    __syncthreads();
  }
  int run = (t == 0) ? 0 : lds[t - 1];
  if (t == 255) part[b] = lds[255];
  #pragma unroll
  for (int j = 0; j < 4; j++) { int idx = base + j; if (idx < n) rp[idx] = run; run += v[j]; }
}

__global__ __launch_bounds__(256) void ca_scan2_kernel(int* __restrict__ part, int nb) {
  __shared__ int lds[256];
  int t = threadIdx.x;
  lds[t] = (t < nb) ? part[t] : 0;
  __syncthreads();
  for (int off = 1; off < 256; off <<= 1) {
    int x = (t >= off) ? lds[t - off] : 0;
    __syncthreads();
    lds[t] += x;
    __syncthreads();
  }
  if (t < nb) part[t] = (t == 0) ? 0 : lds[t - 1];
}

__global__ __launch_bounds__(256) void ca_scan3_kernel(int* __restrict__ rp,
                                                       const int* __restrict__ part,
                                                       int* __restrict__ cacur,
                                                       int n, int total) {
  int b = blockIdx.x, t = threadIdx.x;
  int add = part[b];
  int base = b * 1024 + t * 4;
  #pragma unroll
  for (int j = 0; j < 4; j++) {
    int idx = base + j;
    if (idx < n) { int f = rp[idx] + add; rp[idx] = f; cacur[idx] = f; }
  }
  if (b == 0 && t == 0) rp[n] = total;
}

// Per-bucket finalize for BOTH graphs in one dispatch. Count rows in LDS,
// wave-shfl scan (+16-way cross-wave fixup), write rp/sigma AND the bf16
// sigma-scaled g0 row (fused conversion), then scatter via LDS cursors.
__global__ __launch_bounds__(1024) void fine3_all_kernel(BP P) {
  __shared__ int cnt[1 << S0];
  __shared__ int wsum[16];
  int B = blockIdx.x, t = threadIdx.x;
  int g = (B < P.NBcg) ? 0 : 1;
  int lb = g ? B - P.NBcg : B;
  int s1 = g ? P.s1kg : P.s1cg;
  int sideEnd = g ? P.Nkg : P.Ncg;
  int* rp = g ? P.rp1 : P.rp0;
  int* cv = g ? P.cv1 : P.cv0;
  float* scal = P.scal + (g ? P.Ncg : 0);
  long long g0off = g ? (long long)P.Ncg : 0;
  const float* fB = g ? P.concepts : P.courses;

  int rowbase, rowend;
  if (lb < P.NB0) { rowbase = lb << S0; rowend = min(rowbase + (1 << S0), P.L); }
  else { int bb = lb - P.NB0; rowbase = P.L + (bb << s1); rowend = min(rowbase + (1 << s1), sideEnd); }
  int nrows = rowend - rowbase;
  long long base = rbase(P, g, lb);
  int count = P.gcur[g * 256 + lb] - (int)base;
  int csrbase = P.bkt[g * 256 + lb];

  cnt[t] = 0;
  __syncthreads();
  for (int i = t; i < count; i += 1024) atomicAdd(&cnt[P.binned[base + i] >> 17], 1);
  __syncthreads();
  int deg = cnt[t];
  int lane = t & 63, wid = t >> 6;
  int v = deg;
  #pragma unroll
  for (int off = 1; off < 64; off <<= 1) {
    int y = __shfl_up(v, off);
    if (lane >= off) v += y;
  }
  if (lane == 63) wsum[wid] = v;
  __syncthreads();
  if (t == 0) { int run = 0; for (int w = 0; w < 16; w++) { int x = wsum[w]; wsum[w] = run; run += x; } }
  __syncthreads();
  int pos = csrbase + wsum[wid] + (v - deg);
  cnt[t] = pos;            // reuse as row cursor (all prior cnt reads done)
  if (t < nrows) {
    int row = rowbase + t;
    rp[row] = pos;
    float sg = 1.0f / (sqrtf((float)deg) + 1e-8f);
    scal[row] = sg;
    const float* src = row < P.L ? P.learners + (long long)row * D
                                 : fB + (long long)(row - P.L) * D;
    unsigned short* gdst = P.g0 + (g0off + row) * D;
    #pragma unroll 4
    for (int q = 0; q < 16; q++) {
      float4 x = *(const float4*)(src + q * 4);
      unsigned int lo = f2bf(x.x * sg) | (f2bf(x.y * sg) << 16);
      unsigned int hi = f2bf(x.z * sg) | (f2bf(x.w * sg) << 16);
      *(uint2*)(gdst + q * 4) = make_uint2(lo, hi);
    }
  }
  __syncthreads();
  for (int i = t; i < count; i += 1024) {
    int w = P.binned[base + i];
    int p = atomicAdd(&cnt[w >> 17], 1);
    cv[p] = w & 0x1FFFF;
  }
}

__global__ __launch_bounds__(256) void scatter_ca_kernel(
    const int* __restrict__ rows, const int* __restrict__ cols,
    int* __restrict__ rowcur, int* __restrict__ cv, long long ne) {
  long long e = (long long)blockIdx.x * blockDim.x + threadIdx.x;
  if (e >= ne) return;
  int p = atomicAdd(&rowcur[rows[e]], 1);
  cv[p] = cols[e];
}

// ============================ pull SpMM (16-edge MLP bf16 gather) ============================
template <int MODE, int INITA, int INITB>
__global__ __launch_bounds__(256) void pull4_kernel(
    const int* __restrict__ rowptr, const int* __restrict__ cols,
    const unsigned short* __restrict__ gt, unsigned short* __restrict__ g1,
    const float* __restrict__ sigRow,
    float* __restrict__ accA, float* __restrict__ accB, int splitAcc,
    const float* __restrict__ i0A, const float* __restrict__ i0B, int i0Split,
    float i0ScaleA, float i0ScaleB, int nrows) {
  int row = blockIdx.x * 4 + (threadIdx.x >> 6);
  if (row >= nrows) return;
  int lane = threadIdx.x & 63;
  int sub = lane & 15;
  int grp = lane >> 4;
  int e0 = rowptr[row], e1 = rowptr[row + 1];
  float sx = 0.f, sy = 0.f, sz = 0.f, sw = 0.f;
  long long dimoff = (long long)(sub << 2);
  int e = e0;
  for (; e + 16 <= e1; e += 16) {
    int c0 = cols[e + grp];
    int c1 = cols[e + 4 + grp];
    int c2 = cols[e + 8 + grp];
    int c3 = cols[e + 12 + grp];
    uint2 v0 = *(const uint2*)(gt + ((long long)c0 << 6) + dimoff);
    uint2 v1 = *(const uint2*)(gt + ((long long)c1 << 6) + dimoff);
    uint2 v2 = *(const uint2*)(gt + ((long long)c2 << 6) + dimoff);
    uint2 v3 = *(const uint2*)(gt + ((long long)c3 << 6) + dimoff);
    sx += __uint_as_float(v0.x << 16);
    sy += __uint_as_float(v0.x & 0xFFFF0000u);
    sz += __uint_as_float(v0.y << 16);
    sw += __uint_as_float(v0.y & 0xFFFF0000u);
    sx += __uint_as_float(v1.x << 16);
    sy += __uint_as_float(v1.x & 0xFFFF0000u);
    sz += __uint_as_float(v1.y << 16);
    sw += __uint_as_float(v1.y & 0xFFFF0000u);
    sx += __uint_as_float(v2.x << 16);
    sy += __uint_as_float(v2.x & 0xFFFF0000u);
    sz += __uint_as_float(v2.y << 16);
    sw += __uint_as_float(v2.y & 0xFFFF0000u);
    sx += __uint_as_float(v3.x << 16);
    sy += __uint_as_float(v3.x & 0xFFFF0000u);
    sz += __uint_as_float(v3.y << 16);
    sw += __uint_as_float(v3.y & 0xFFFF0000u);
  }
  for (int ee = e + grp; ee < e1; ee += 4) {
    int c = cols[ee];
    uint2 v = *(const uint2*)(gt + ((long long)c << 6) + dimoff);
    sx += __uint_as_float(v.x << 16);
    sy += __uint_as_float(v.x & 0xFFFF0000u);
    sz += __uint_as_float(v.y << 16);
    sw += __uint_as_float(v.y & 0xFFFF0000u);
  }
  #pragma unroll
  for (int off = 16; off <= 32; off <<= 1) {
    sx += __shfl_xor(sx, off);
    sy += __shfl_xor(sy, off);
    sz += __shfl_xor(sz, off);
    sw += __shfl_xor(sw, off);
  }
  float q = sx * sx + sy * sy + sz * sz + sw * sw;
  #pragma unroll
  for (int off = 1; off <= 8; off <<= 1) q += __shfl_xor(q, off);
  float r = 1.0f / fmaxf(sqrtf(q), 1e-12f);

  if (grp == 0) {
    long long off4 = dimoff;
    if (MODE == 0) {
      float sg = sigRow[row];
      float f = sg * sg;
      unsigned int lo = f2bf(f * sx) | (f2bf(f * sy) << 16);
      unsigned int hi = f2bf(f * sz) | (f2bf(f * sw) << 16);
      *(uint2*)(g1 + ((long long)row << 6) + (sub << 2)) = make_uint2(lo, hi);
    }
    float4 base;
    float* dst;
    if (row < splitAcc) {
      dst = accA + ((long long)row << 6);
      if (INITA) {
        bool lo_ = row < i0Split;
        const float* src = lo_ ? i0A + ((long long)row << 6)
                               : i0B + ((long long)(row - i0Split) << 6);
        float sc = lo_ ? i0ScaleA : i0ScaleB;
        float4 v = *(const float4*)(src + off4);
        base = make_float4(sc * v.x, sc * v.y, sc * v.z, sc * v.w);
      } else base = *(const float4*)(dst + off4);
    } else {
      dst = accB + ((long long)(row - splitAcc) << 6);
      if (INITB) {
        const float* src = i0B + ((long long)(row - i0Split) << 6);
        float4 v = *(const float4*)(src + off4);
        base = make_float4(i0ScaleB * v.x, i0ScaleB * v.y, i0ScaleB * v.z, i0ScaleB * v.w);
      } else base = *(const float4*)(dst + off4);
    }
    *(float4*)(dst + off4) = make_float4(base.x + sx * r, base.y + sy * r,
                                         base.z + sz * r, base.w + sw * r);
  }
}

__global__ __launch_bounds__(256) void pull_ca_kernel(
    const int* __restrict__ rowptr, const int* __restrict__ cols,
    const float* __restrict__ invdeg, const float* __restrict__ feat,
    float* __restrict__ acc, int nrows) {
  int row = blockIdx.x * 4 + (threadIdx.x >> 6);
  if (row >= nrows) return;
  int lane = threadIdx.x & 63;
  int e0 = rowptr[row], e1 = rowptr[row + 1];
  float s = 0.f;
  for (int e = e0; e < e1; ++e) s += feat[((long long)cols[e] << 6) + lane];
  acc[((long long)row << 6) + lane] += invdeg[row] * s;
}

// ============================ fallback (atomic push path) ============================

__global__ __launch_bounds__(256) void spmm_atomic_kernel(
    const int* __restrict__ rows, const int* __restrict__ cols,
    const float* __restrict__ vals, const float* __restrict__ feat,
    float* __restrict__ outp, long long ne) {
  long long t = (long long)blockIdx.x * blockDim.x + threadIdx.x;
  long long e = t >> 4;
  if (e >= ne) return;
  int lane = (int)(t & 15);
  int r = rows[e];
  int c = cols[e];
  float v = vals[e];
  const float4 f = *(const float4*)(feat + (long long)c * D + lane * 4);
  float* o = outp + (long long)r * D + lane * 4;
  atomicAdd(o + 0, v * f.x);
  atomicAdd(o + 1, v * f.y);
  atomicAdd(o + 2, v * f.z);
  atomicAdd(o + 3, v * f.w);
}

__global__ __launch_bounds__(256) void norm_acc_kernel(const float* __restrict__ feat,
                                                       float* __restrict__ acc,
                                                       int nrows) {
  int row = blockIdx.x * 4 + (threadIdx.x >> 6);
  if (row >= nrows) return;
  int lane = threadIdx.x & 63;
  float x = feat[(long long)row * D + lane];
  float s = x * x;
  #pragma unroll
  for (int off = 32; off; off >>= 1) s += __shfl_xor(s, off);
  float sc = 1.0f / fmaxf(sqrtf(s), 1e-12f);
  acc[(long long)row * D + lane] += x * sc;
}

// ============================ launch ============================

extern "C" void kernel_launch(void* const* d_in, const int* in_sizes, int n_in,
                              void* d_out, int out_size, void* d_ws, size_t ws_size,
                              hipStream_t stream) {
  const float* learners = (const float*)d_in[0];
  const float* courses  = (const float*)d_in[1];
  const float* concepts = (const float*)d_in[2];
  const int*   cg_rows  = (const int*)d_in[3];
  const int*   cg_cols  = (const int*)d_in[4];
  const int*   kg_rows  = (const int*)d_in[6];
  const int*   kg_cols  = (const int*)d_in[7];
  const int*   ca_rows  = (const int*)d_in[9];
  const int*   ca_cols  = (const int*)d_in[10];
  const float* cg_vals  = (const float*)d_in[5];
  const float* kg_vals  = (const float*)d_in[8];
  const float* ca_vals  = (const float*)d_in[11];

  const long long Lr  = in_sizes[0] / D;
  const long long Cr  = in_sizes[1] / D;
  const long long Kr  = in_sizes[2] / D;
  const long long Ecg = in_sizes[3];
  const long long Ekg = in_sizes[6];
  const long long Eca = in_sizes[9];
  const long long EcgH = Ecg / 2;
  const long long EkgH = Ekg / 2;
  const long long Ncg = Lr + Cr;
  const long long Nkg = Lr + Kr;

  float* out = (float*)d_out;

  const int NB0   = (int)((Lr + (1 << S0) - 1) >> S0);
  const int s1cg  = 8;
  const int s1kg  = 6;
  const int NB1cg = (int)((Cr + (1 << s1cg) - 1) >> s1cg);
  const int NB1kg = (int)((Kr + (1 << s1kg) - 1) >> s1kg);
  const int NBcg  = NB0 + NB1cg;
  const int NBkg  = NB0 + NB1kg;

  // padded bucket-region capacities (2x mean: binomial bucket sums concentrate to ~1%)
  const int capcg0 = 2 * (int)((EcgH + NB0 - 1) / NB0);
  const int capcg1 = 2 * (int)((EcgH + NB1cg - 1) / NB1cg);
  const int capkg0 = 2 * (int)((EkgH + NB0 - 1) / NB0);
  const int capkg1 = 2 * (int)((EkgH + NB1kg - 1) / NB1kg);
  const long long padcg = (long long)NB0 * capcg0 + (long long)NB1cg * capcg1;
  const long long padkg = (long long)NB0 * capkg0 + (long long)NB1kg * capkg1;
  const long long padtot = padcg + padkg;

  // ---- workspace layout (words) ----
  long long maxN = (Ncg > Nkg ? Ncg : Nkg);
  long long shareW = padtot > maxN * 32 ? padtot : maxN * 32;  // padded binned / g1
  size_t need = 0;
  auto walloc = [&](long long elems) { size_t off = need; need += ((size_t)elems + 3) & ~(size_t)3; return off; };
  int* wsbase = (int*)d_ws;
  size_t o_share = walloc(shareW);
  size_t o_g0    = walloc((Ncg + Nkg) * 32);
  size_t o_acck  = walloc(Kr * D);
  size_t o_rp0   = walloc(Ncg + 1);
  size_t o_rp1   = walloc(Nkg + 1);
  size_t o_rp2   = walloc(Cr + 1);
  size_t o_cv0   = walloc(Ecg);
  size_t o_cv1   = walloc(Ekg);
  size_t o_cv2   = walloc(Eca);
  size_t o_gcur  = walloc(512);
  size_t o_bkt   = walloc(512);
  size_t o_cadeg = walloc(Cr);
  size_t o_scal  = walloc(Ncg + Nkg + Cr);
  size_t o_part  = walloc(512);
  size_t o_cacur = walloc(Cr);

  auto axcopy = [&](float* dst, const float* src, long long n, float s) {
    long long n4 = n / 4;
    long long b = (n4 + 255) / 256;
    int blocks = (int)(b < 2048 ? b : 2048);
    axcopy_kernel<<<blocks, 256, 0, stream>>>(dst, src, n4, s);
  };

  bool packable = (Ncg <= 131072) && (Nkg <= 131072) &&
                  (NBcg <= 256) && (NBkg <= 256) &&
                  (Ecg % 2 == 0) && (Ekg % 2 == 0) && (Lr >= 1);
  if (need * 4 > ws_size || !packable) {
    // -------- fallback: atomic push path (correct for any shape) --------
    float* buf0 = (float*)d_ws;
    float* buf1 = buf0 + Ncg * D;
    float* acck = buf1 + Ncg * D;
    auto spmm = [&](const int* r, const int* c, const float* v, const float* f,
                    float* o, long long ne) {
      long long threads = ne * 16;
      int blocks = (int)((threads + 255) / 256);
      spmm_atomic_kernel<<<blocks, 256, 0, stream>>>(r, c, v, f, o, ne);
    };
    auto normacc = [&](const float* f, float* a, long long nrows) {
      int blocks = (int)((nrows + 3) / 4);
      norm_acc_kernel<<<blocks, 256, 0, stream>>>(f, a, (int)nrows);
    };
    axcopy(buf0, learners, Lr * D, 1.f);
    axcopy(buf0 + Lr * D, courses, Cr * D, 1.f);
    axcopy(out, learners, Lr * D, 2.f);
    axcopy(out + Lr * D, courses, Cr * D, 1.f);
    hipMemsetAsync(buf1, 0, (size_t)(Ncg * D) * sizeof(float), stream);
    spmm(cg_rows, cg_cols, cg_vals, buf0, buf1, Ecg);
    normacc(buf1, out, Ncg);
    hipMemsetAsync(buf0, 0, (size_t)(Ncg * D) * sizeof(float), stream);
    spmm(cg_rows, cg_cols, cg_vals, buf1, buf0, Ecg);
    normacc(buf0, out, Ncg);
    axcopy(buf0, learners, Lr * D, 1.f);
    axcopy(buf0 + Lr * D, concepts, Kr * D, 1.f);
    axcopy(acck, concepts, Kr * D, 1.f);
    hipMemsetAsync(buf1, 0, (size_t)(Nkg * D) * sizeof(float), stream);
    spmm(kg_rows, kg_cols, kg_vals, buf0, buf1, Ekg);
    normacc(buf1, out, Lr);
    normacc(buf1 + Lr * D, acck, Kr);
    hipMemsetAsync(buf0, 0, (size_t)(Nkg * D) * sizeof(float), stream);
    spmm(kg_rows, kg_cols, kg_vals, buf1, buf0, Ekg);
    normacc(buf0, out, Lr);
    normacc(buf0 + Lr * D, acck, Kr);
    spmm(ca_rows, ca_cols, ca_vals, acck, out + Lr * D, Eca);
    return;
  }

  int*            binned = wsbase + o_share;
  unsigned short* g1     = (unsigned short*)(wsbase + o_share);  // disjoint lifetime
  unsigned short* g0     = (unsigned short*)(wsbase + o_g0);
  float* acck   = (float*)(wsbase + o_acck);
  int*   rp0    = wsbase + o_rp0;
  int*   rp1    = wsbase + o_rp1;
  int*   rp2    = wsbase + o_rp2;
  int*   cv0    = wsbase + o_cv0;
  int*   cv1    = wsbase + o_cv1;
  int*   cv2    = wsbase + o_cv2;
  int*   gcur   = wsbase + o_gcur;
  int*   bkt    = wsbase + o_bkt;
  int*   cadeg  = wsbase + o_cadeg;
  float* scal   = (float*)(wsbase + o_scal);
  int*   part   = wsbase + o_part;
  int*   cacur  = wsbase + o_cacur;

  BP P;
  P.cgr = cg_rows; P.cgc = cg_cols; P.kgr = kg_rows; P.kgc = kg_cols; P.car = ca_rows;
  P.EcgH = EcgH; P.EkgH = EkgH; P.Eca = Eca; P.Ecg = Ecg; P.Ekg = Ekg;
  P.Bcg = (int)((EcgH + EPB - 1) / EPB);
  P.Bkg = (int)((EkgH + EPB - 1) / EPB);
  P.L = (int)Lr; P.Ncg = (int)Ncg; P.Nkg = (int)Nkg;
  P.NB0 = NB0; P.NBcg = NBcg; P.NBkg = NBkg; P.s1cg = s1cg; P.s1kg = s1kg;
  P.capcg0 = capcg0; P.capcg1 = capcg1; P.capkg0 = capkg0; P.capkg1 = capkg1;
  P.padcg = padcg;
  P.gcur = gcur; P.bkt = bkt; P.cadeg = cadeg; P.binned = binned;
  P.rp0 = rp0; P.rp1 = rp1; P.cv0 = cv0; P.cv1 = cv1;
  P.scal = scal; P.g0 = g0;
  P.learners = learners; P.courses = courses; P.concepts = concepts;

  const int Bca = (int)((Eca + EPB - 1) / EPB);

  // ---- build ----
  hipMemsetAsync(cadeg, 0, (size_t)Cr * sizeof(int), stream);
  init_gcur_kernel<<<1, 512, 0, stream>>>(P);
  binD_all_kernel<<<P.Bcg + P.Bkg + Bca, 256, 0, stream>>>(P);
  scan_all_kernel<<<1, 256, 0, stream>>>(P);

  const int nbca = (int)((Cr + 1023) / 1024);
  ca_scan1_kernel<<<nbca, 256, 0, stream>>>(cadeg, rp2, scal + Ncg + Nkg, part, (int)Cr);
  ca_scan2_kernel<<<1, 256, 0, stream>>>(part, nbca);
  ca_scan3_kernel<<<nbca, 256, 0, stream>>>(rp2, part, cacur, (int)Cr, (int)Eca);

  fine3_all_kernel<<<NBcg + NBkg, 1024, 0, stream>>>(P);
  scatter_ca_kernel<<<(int)((Eca + 255) / 256), 256, 0, stream>>>(ca_rows, ca_cols, cacur, cv2, Eca);

  const unsigned short* g0cg = g0;
  const unsigned short* g0kg = g0 + (long long)Ncg * D;
  const float* sig_cg = scal;
  const float* sig_kg = scal + Ncg;
  const float* inv_ca = scal + Ncg + Nkg;

  // ---- course-grained view ----
  {
    int blocks = (int)((Ncg + 3) / 4);
    pull4_kernel<0, 1, 1><<<blocks, 256, 0, stream>>>(
        rp0, cv0, g0cg, g1, sig_cg,
        out, out, (int)Ncg,
        learners, courses, (int)Lr, 2.0f, 1.0f, (int)Ncg);
    pull4_kernel<1, 0, 0><<<blocks, 256, 0, stream>>>(
        rp0, cv0, g1, nullptr, nullptr,
        out, out, (int)Ncg,
        nullptr, nullptr, 0, 0.f, 0.f, (int)Ncg);
  }

  // ---- concept-grained view ----
  {
    int blocks = (int)((Nkg + 3) / 4);
    pull4_kernel<0, 0, 1><<<blocks, 256, 0, stream>>>(
        rp1, cv1, g0kg, g1, sig_kg,
        out, acck, (int)Lr,
        nullptr, concepts, (int)Lr, 0.f, 1.0f, (int)Nkg);
    pull4_kernel<1, 0, 0><<<blocks, 256, 0, stream>>>(
        rp1, cv1, g1, nullptr, nullptr,
        out, acck, (int)Lr,
        nullptr, nullptr, 0, 0.f, 0.f, (int)Nkg);
  }

  // ---- aggregate concept features into course rows ----
  {
    int blocks = (int)((Cr + 3) / 4);
    pull_ca_kernel<<<blocks, 256, 0, stream>>>(rp2, cv2, inv_ca, acck,
                                               out + Lr * D, (int)Cr);
  }
}

// Round 12
// 665.432 us; speedup vs baseline: 1.0798x; 1.0798x over previous
//
#include <hip/hip_runtime.h>

#define D 64
#define S0 10           // learner-side bucket shift (1024 rows/bucket)
#define BCHUNK 8        // edges per thread in bin pass

// bkt[] layout (ints): see R7
#define BKT_CNTCG 0
#define BKT_CNTKG 256
#define BKT_BASECG 512
#define BKT_BASEKG 772
#define BKT_CURCG 1032
#define BKT_CURKG 1288
#define BKT_WORDS 2048

__device__ __forceinline__ unsigned int f2bf(float x) {
  unsigned int u = __float_as_uint(x);
  return (u + 0x7FFFu + ((u >> 16) & 1u)) >> 16;
}

// ============================ element-wise utils (fallback only) ============================

__global__ __launch_bounds__(256) void axcopy_kernel(float* __restrict__ dst,
                                                     const float* __restrict__ src,
                                                     long long n4, float s) {
  long long i = (long long)blockIdx.x * blockDim.x + threadIdx.x;
  long long stride = (long long)gridDim.x * blockDim.x;
  for (; i < n4; i += stride) {
    float4 v = ((const float4*)src)[i];
    v.x *= s; v.y *= s; v.z *= s; v.w *= s;
    ((float4*)dst)[i] = v;
  }
}

// ============================ build ============================

// Pass A: bucket-occupancy counts in LDS (512 bins), one flush per block.
__global__ __launch_bounds__(1024) void bincnt_kernel(
    const int* __restrict__ cgr, const int* __restrict__ cgc, long long EcgH,
    const int* __restrict__ kgr, const int* __restrict__ kgc, long long EkgH,
    const int* __restrict__ car, long long Eca,
    int* __restrict__ bkt, int* __restrict__ cadeg,
    int L, int NB0, int s1cg, int s1kg) {
  __shared__ int h[512];
  int t = threadIdx.x;
  if (t < 512) h[t] = 0;
  __syncthreads();
  long long i = (long long)blockIdx.x * blockDim.x + t;
  long long stride = (long long)gridDim.x * blockDim.x;
  long long t01 = EcgH + EkgH, tot = t01 + Eca;
  for (; i < tot; i += stride) {
    if (i < EcgH) {
      int a = cgr[i], c = cgc[i];
      atomicAdd(&h[a >> S0], 1);
      atomicAdd(&h[NB0 + ((c - L) >> s1cg)], 1);
    } else if (i < t01) {
      long long j = i - EcgH;
      int a = kgr[j], c = kgc[j];
      atomicAdd(&h[256 + (a >> S0)], 1);
      atomicAdd(&h[256 + NB0 + ((c - L) >> s1kg)], 1);
    } else {
      long long j = i - t01;
      atomicAdd(&cadeg[car[j]], 1);
    }
  }
  __syncthreads();
  if (t < 512 && h[t]) atomicAdd(&bkt[t], h[t]);
}

__global__ __launch_bounds__(256) void bktscan_kernel(int* __restrict__ bkt,
                                                      int NBcg, int NBkg) {
  __shared__ int lds[256];
  int t = threadIdx.x;
  #pragma unroll
  for (int g = 0; g < 2; ++g) {
    int NB      = g ? NBkg : NBcg;
    int cntoff  = g ? BKT_CNTKG : BKT_CNTCG;
    int baseoff = g ? BKT_BASEKG : BKT_BASECG;
    int curoff  = g ? BKT_CURKG : BKT_CURCG;
    lds[t] = (t < NB) ? bkt[cntoff + t] : 0;
    __syncthreads();
    for (int off = 1; off < 256; off <<= 1) {
      int x = (t >= off) ? lds[t - off] : 0;
      __syncthreads();
      lds[t] += x;
      __syncthreads();
    }
    int excl = (t == 0) ? 0 : lds[t - 1];
    if (t < NB) { bkt[baseoff + t] = excl; bkt[curoff + t] = excl; }
    if (t == NB - 1) bkt[baseoff + NB] = lds[t];
    __syncthreads();
  }
}

__global__ __launch_bounds__(256) void ca_scan1_kernel(const int* __restrict__ deg,
                                                       int* __restrict__ rp,
                                                       float* __restrict__ scal,
                                                       int* __restrict__ part, int n) {
  __shared__ int lds[256];
  int b = blockIdx.x, t = threadIdx.x;
  int base = b * 1024 + t * 4;
  int v[4]; int s = 0;
  #pragma unroll
  for (int j = 0; j < 4; j++) {
    int idx = base + j;
    v[j] = (idx < n) ? deg[idx] : 0;
    if (idx < n) scal[idx] = 1.0f / ((float)v[j] + 1e-8f);
    s += v[j];
  }
  lds[t] = s;
  __syncthreads();
  for (int off = 1; off < 256; off <<= 1) {
    int x = (t >= off) ? lds[t - off] : 0;
    __syncthreads();
    lds[t] += x;
    __syncthreads();
  }
  int run = (t == 0) ? 0 : lds[t - 1];
  if (t == 255) part[b] = lds[255];
  #pragma unroll
  for (int j = 0; j < 4; j++) { int idx = base + j; if (idx < n) rp[idx] = run; run += v[j]; }
}

__global__ __launch_bounds__(256) void ca_scan2_kernel(int* __restrict__ part, int nb) {
  __shared__ int lds[256];
  int t = threadIdx.x;
  lds[t] = (t < nb) ? part[t] : 0;
  __syncthreads();
  for (int off = 1; off < 256; off <<= 1) {
    int x = (t >= off) ? lds[t - off] : 0;
    __syncthreads();
    lds[t] += x;
    __syncthreads();
  }
  if (t < nb) part[t] = (t == 0) ? 0 : lds[t - 1];
}

__global__ __launch_bounds__(256) void ca_scan3_kernel(int* __restrict__ rp,
                                                       const int* __restrict__ part,
                                                       int* __restrict__ cacur,
                                                       int n, int total) {
  int b = blockIdx.x, t = threadIdx.x;
  int add = part[b];
  int base = b * 1024 + t * 4;
  #pragma unroll
  for (int j = 0; j < 4; j++) {
    int idx = base + j;
    if (idx < n) { int f = rp[idx] + add; rp[idx] = f; cacur[idx] = f; }
  }
  if (b == 0 && t == 0) rp[n] = total;
}

__global__ __launch_bounds__(256) void bin_kernel(
    const int* __restrict__ rowsA, const int* __restrict__ colsA, long long E,
    int L, int s1, int NB0, int NBtot,
    int* __restrict__ gcur, int* __restrict__ binned) {
  __shared__ int cnt[256];
  __shared__ int gbase[256];
  int t = threadIdx.x;
  long long base = (long long)blockIdx.x * (256 * BCHUNK);
  cnt[t] = 0;
  __syncthreads();
  int av[BCHUNK], cv_[BCHUNK], l0[BCHUNK], l1[BCHUNK];
  #pragma unroll
  for (int k = 0; k < BCHUNK; k++) {
    long long i = base + (long long)k * 256 + t;
    bool ok = i < E;
    int a = ok ? rowsA[i] : 0;
    int c = ok ? colsA[i] : L;
    av[k] = a; cv_[k] = c;
    if (ok) {
      int b0 = a >> S0;
      int b1 = NB0 + ((c - L) >> s1);
      l0[k] = atomicAdd(&cnt[b0], 1);
      l1[k] = atomicAdd(&cnt[b1], 1);
    } else { l0[k] = 0; l1[k] = 0; }
  }
  __syncthreads();
  if (t < NBtot) gbase[t] = cnt[t] ? atomicAdd(&gcur[t], cnt[t]) : 0;
  __syncthreads();
  #pragma unroll
  for (int k = 0; k < BCHUNK; k++) {
    long long i = base + (long long)k * 256 + t;
    if (i < E) {
      int a = av[k], c = cv_[k];
      int b0 = a >> S0;
      int b1 = NB0 + ((c - L) >> s1);
      binned[gbase[b0] + l0[k]] = ((a & ((1 << S0) - 1)) << 17) | c;
      binned[gbase[b1] + l1[k]] = (((c - L) & ((1 << s1) - 1)) << 17) | a;
    }
  }
}

// Per-bucket finalize (one graph per dispatch — keeps concurrent scatter-window
// footprint <= aggregate L2; the R11 merged version thrashed). Count per-row
// degrees in LDS, wave-shfl scan, write rp/sigma, COALESCED fused bf16 g0
// conversion (16-lane groups per row), then scatter via LDS cursors.
__global__ __launch_bounds__(1024) void fine2_kernel(
    const int* __restrict__ binned, const int* __restrict__ bktbase,
    int* __restrict__ rp, int* __restrict__ cvout, float* __restrict__ scal,
    const float* __restrict__ fA, const float* __restrict__ fB,
    unsigned short* __restrict__ g0g,
    int L, int sideEnd, int s1, int NB0, int nfull) {
  __shared__ int cnt[1 << S0];
  __shared__ int wsum[16];
  int b = blockIdx.x, t = threadIdx.x;
  int rowbase, rowend;
  if (b < NB0) { rowbase = b << S0; rowend = min(rowbase + (1 << S0), L); }
  else { int bb = b - NB0; rowbase = L + (bb << s1); rowend = min(rowbase + (1 << s1), sideEnd); }
  int nrows = rowend - rowbase;
  int base = bktbase[b], end = bktbase[b + 1];
  cnt[t] = 0;
  __syncthreads();
  for (int i = base + t; i < end; i += 1024) atomicAdd(&cnt[binned[i] >> 17], 1);
  __syncthreads();
  int deg = cnt[t];
  int lane = t & 63, wid = t >> 6;
  int v = deg;
  #pragma unroll
  for (int off = 1; off < 64; off <<= 1) {
    int y = __shfl_up(v, off);
    if (lane >= off) v += y;
  }
  if (lane == 63) wsum[wid] = v;
  __syncthreads();
  if (t == 0) { int run = 0; for (int w = 0; w < 16; w++) { int x = wsum[w]; wsum[w] = run; run += x; } }
  __syncthreads();
  int pos = base + wsum[wid] + (v - deg);
  cnt[t] = pos;            // reuse as row cursor
  if (t < nrows) {
    rp[rowbase + t] = pos;
    scal[rowbase + t] = 1.0f / (sqrtf((float)deg) + 1e-8f);
  }
  if (b == gridDim.x - 1 && t == 0) rp[nfull] = end;
  __syncthreads();   // cursors + scal visible block-wide

  // fused coalesced g0 conversion: each wave converts 4 rows/iter (16 lanes/row)
  for (int r0 = wid * 4 + (lane >> 4); r0 < nrows; r0 += 64) {
    int row = rowbase + r0;
    float sg = scal[row];
    int sub = lane & 15;
    const float* src = (row < L ? fA + (long long)row * D
                                : fB + (long long)(row - L) * D) + sub * 4;
    float4 x = *(const float4*)src;
    unsigned int lo = f2bf(x.x * sg) | (f2bf(x.y * sg) << 16);
    unsigned int hi = f2bf(x.z * sg) | (f2bf(x.w * sg) << 16);
    *(uint2*)(g0g + (long long)row * D + sub * 4) = make_uint2(lo, hi);
  }

  for (int i = base + t; i < end; i += 1024) {
    int w = binned[i];
    int p = atomicAdd(&cnt[w >> 17], 1);
    cvout[p] = w & 0x1FFFF;
  }
}

__global__ __launch_bounds__(256) void scatter_ca_kernel(
    const int* __restrict__ rows, const int* __restrict__ cols,
    int* __restrict__ rowcur, int* __restrict__ cv, long long ne) {
  long long e = (long long)blockIdx.x * blockDim.x + threadIdx.x;
  if (e >= ne) return;
  int p = atomicAdd(&rowcur[rows[e]], 1);
  cv[p] = cols[e];
}

// ============================ pull SpMM (16-edge MLP bf16 gather) ============================
template <int MODE, int INITA, int INITB>
__global__ __launch_bounds__(256) void pull4_kernel(
    const int* __restrict__ rowptr, const int* __restrict__ cols,
    const unsigned short* __restrict__ gt, unsigned short* __restrict__ g1,
    const float* __restrict__ sigRow,
    float* __restrict__ accA, float* __restrict__ accB, int splitAcc,
    const float* __restrict__ i0A, const float* __restrict__ i0B, int i0Split,
    float i0ScaleA, float i0ScaleB, int nrows) {
  int row = blockIdx.x * 4 + (threadIdx.x >> 6);
  if (row >= nrows) return;
  int lane = threadIdx.x & 63;
  int sub = lane & 15;
  int grp = lane >> 4;
  int e0 = rowptr[row], e1 = rowptr[row + 1];
  float sx = 0.f, sy = 0.f, sz = 0.f, sw = 0.f;
  long long dimoff = (long long)(sub << 2);
  int e = e0;
  for (; e + 16 <= e1; e += 16) {
    int c0 = cols[e + grp];
    int c1 = cols[e + 4 + grp];
    int c2 = cols[e + 8 + grp];
    int c3 = cols[e + 12 + grp];
    uint2 v0 = *(const uint2*)(gt + ((long long)c0 << 6) + dimoff);
    uint2 v1 = *(const uint2*)(gt + ((long long)c1 << 6) + dimoff);
    uint2 v2 = *(const uint2*)(gt + ((long long)c2 << 6) + dimoff);
    uint2 v3 = *(const uint2*)(gt + ((long long)c3 << 6) + dimoff);
    sx += __uint_as_float(v0.x << 16);
    sy += __uint_as_float(v0.x & 0xFFFF0000u);
    sz += __uint_as_float(v0.y << 16);
    sw += __uint_as_float(v0.y & 0xFFFF0000u);
    sx += __uint_as_float(v1.x << 16);
    sy += __uint_as_float(v1.x & 0xFFFF0000u);
    sz += __uint_as_float(v1.y << 16);
    sw += __uint_as_float(v1.y & 0xFFFF0000u);
    sx += __uint_as_float(v2.x << 16);
    sy += __uint_as_float(v2.x & 0xFFFF0000u);
    sz += __uint_as_float(v2.y << 16);
    sw += __uint_as_float(v2.y & 0xFFFF0000u);
    sx += __uint_as_float(v3.x << 16);
    sy += __uint_as_float(v3.x & 0xFFFF0000u);
    sz += __uint_as_float(v3.y << 16);
    sw += __uint_as_float(v3.y & 0xFFFF0000u);
  }
  for (int ee = e + grp; ee < e1; ee += 4) {
    int c = cols[ee];
    uint2 v = *(const uint2*)(gt + ((long long)c << 6) + dimoff);
    sx += __uint_as_float(v.x << 16);
    sy += __uint_as_float(v.x & 0xFFFF0000u);
    sz += __uint_as_float(v.y << 16);
    sw += __uint_as_float(v.y & 0xFFFF0000u);
  }
  #pragma unroll
  for (int off = 16; off <= 32; off <<= 1) {
    sx += __shfl_xor(sx, off);
    sy += __shfl_xor(sy, off);
    sz += __shfl_xor(sz, off);
    sw += __shfl_xor(sw, off);
  }
  float q = sx * sx + sy * sy + sz * sz + sw * sw;
  #pragma unroll
  for (int off = 1; off <= 8; off <<= 1) q += __shfl_xor(q, off);
  float r = 1.0f / fmaxf(sqrtf(q), 1e-12f);

  if (grp == 0) {
    long long off4 = dimoff;
    if (MODE == 0) {
      float sg = sigRow[row];
      float f = sg * sg;
      unsigned int lo = f2bf(f * sx) | (f2bf(f * sy) << 16);
      unsigned int hi = f2bf(f * sz) | (f2bf(f * sw) << 16);
      *(uint2*)(g1 + ((long long)row << 6) + (sub << 2)) = make_uint2(lo, hi);
    }
    float4 base;
    float* dst;
    if (row < splitAcc) {
      dst = accA + ((long long)row << 6);
      if (INITA) {
        bool lo_ = row < i0Split;
        const float* src = lo_ ? i0A + ((long long)row << 6)
                               : i0B + ((long long)(row - i0Split) << 6);
        float sc = lo_ ? i0ScaleA : i0ScaleB;
        float4 v = *(const float4*)(src + off4);
        base = make_float4(sc * v.x, sc * v.y, sc * v.z, sc * v.w);
      } else base = *(const float4*)(dst + off4);
    } else {
      dst = accB + ((long long)(row - splitAcc) << 6);
      if (INITB) {
        const float* src = i0B + ((long long)(row - i0Split) << 6);
        float4 v = *(const float4*)(src + off4);
        base = make_float4(i0ScaleB * v.x, i0ScaleB * v.y, i0ScaleB * v.z, i0ScaleB * v.w);
      } else base = *(const float4*)(dst + off4);
    }
    *(float4*)(dst + off4) = make_float4(base.x + sx * r, base.y + sy * r,
                                         base.z + sz * r, base.w + sw * r);
  }
}

__global__ __launch_bounds__(256) void pull_ca_kernel(
    const int* __restrict__ rowptr, const int* __restrict__ cols,
    const float* __restrict__ invdeg, const float* __restrict__ feat,
    float* __restrict__ acc, int nrows) {
  int row = blockIdx.x * 4 + (threadIdx.x >> 6);
  if (row >= nrows) return;
  int lane = threadIdx.x & 63;
  int e0 = rowptr[row], e1 = rowptr[row + 1];
  float s = 0.f;
  for (int e = e0; e < e1; ++e) s += feat[((long long)cols[e] << 6) + lane];
  acc[((long long)row << 6) + lane] += invdeg[row] * s;
}

// ============================ fallback (atomic push path) ============================

__global__ __launch_bounds__(256) void spmm_atomic_kernel(
    const int* __restrict__ rows, const int* __restrict__ cols,
    const float* __restrict__ vals, const float* __restrict__ feat,
    float* __restrict__ outp, long long ne) {
  long long t = (long long)blockIdx.x * blockDim.x + threadIdx.x;
  long long e = t >> 4;
  if (e >= ne) return;
  int lane = (int)(t & 15);
  int r = rows[e];
  int c = cols[e];
  float v = vals[e];
  const float4 f = *(const float4*)(feat + (long long)c * D + lane * 4);
  float* o = outp + (long long)r * D + lane * 4;
  atomicAdd(o + 0, v * f.x);
  atomicAdd(o + 1, v * f.y);
  atomicAdd(o + 2, v * f.z);
  atomicAdd(o + 3, v * f.w);
}

__global__ __launch_bounds__(256) void norm_acc_kernel(const float* __restrict__ feat,
                                                       float* __restrict__ acc,
                                                       int nrows) {
  int row = blockIdx.x * 4 + (threadIdx.x >> 6);
  if (row >= nrows) return;
  int lane = threadIdx.x & 63;
  float x = feat[(long long)row * D + lane];
  float s = x * x;
  #pragma unroll
  for (int off = 32; off; off >>= 1) s += __shfl_xor(s, off);
  float sc = 1.0f / fmaxf(sqrtf(s), 1e-12f);
  acc[(long long)row * D + lane] += x * sc;
}

// ============================ launch ============================

extern "C" void kernel_launch(void* const* d_in, const int* in_sizes, int n_in,
                              void* d_out, int out_size, void* d_ws, size_t ws_size,
                              hipStream_t stream) {
  const float* learners = (const float*)d_in[0];
  const float* courses  = (const float*)d_in[1];
  const float* concepts = (const float*)d_in[2];
  const int*   cg_rows  = (const int*)d_in[3];
  const int*   cg_cols  = (const int*)d_in[4];
  const int*   kg_rows  = (const int*)d_in[6];
  const int*   kg_cols  = (const int*)d_in[7];
  const int*   ca_rows  = (const int*)d_in[9];
  const int*   ca_cols  = (const int*)d_in[10];
  const float* cg_vals  = (const float*)d_in[5];
  const float* kg_vals  = (const float*)d_in[8];
  const float* ca_vals  = (const float*)d_in[11];

  const long long Lr  = in_sizes[0] / D;
  const long long Cr  = in_sizes[1] / D;
  const long long Kr  = in_sizes[2] / D;
  const long long Ecg = in_sizes[3];
  const long long Ekg = in_sizes[6];
  const long long Eca = in_sizes[9];
  const long long EcgH = Ecg / 2;
  const long long EkgH = Ekg / 2;
  const long long Ncg = Lr + Cr;
  const long long Nkg = Lr + Kr;

  float* out = (float*)d_out;

  const int NB0   = (int)((Lr + (1 << S0) - 1) >> S0);
  const int s1cg  = 8;
  const int s1kg  = 6;
  const int NBcg  = NB0 + (int)((Cr + (1 << s1cg) - 1) >> s1cg);
  const int NBkg  = NB0 + (int)((Kr + (1 << s1kg) - 1) >> s1kg);

  // ---- workspace layout (words) ----
  long long maxE = (Ecg > Ekg ? Ecg : Ekg);
  long long maxN = (Ncg > Nkg ? Ncg : Nkg);
  long long shareW = maxE > maxN * 32 ? maxE : maxN * 32;  // binned (ints) / g1 (ushorts)
  size_t need = 0;
  auto walloc = [&](long long elems) { size_t off = need; need += ((size_t)elems + 3) & ~(size_t)3; return off; };
  int* wsbase = (int*)d_ws;
  size_t o_share = walloc(shareW);                  // binned scratch, then g1
  size_t o_g0    = walloc((Ncg + Nkg) * 32);        // bf16 sigma-scaled feat0 tables
  size_t o_acck  = walloc(Kr * D);
  size_t o_rp0   = walloc(Ncg + 1);
  size_t o_rp1   = walloc(Nkg + 1);
  size_t o_rp2   = walloc(Cr + 1);
  size_t o_cv0   = walloc(Ecg);
  size_t o_cv1   = walloc(Ekg);
  size_t o_cv2   = walloc(Eca);
  size_t o_bkt   = walloc(BKT_WORDS);
  size_t o_cadeg = walloc(Cr);
  size_t o_scal  = walloc(Ncg + Nkg + Cr);
  size_t o_part  = walloc(512);
  size_t o_cacur = walloc(Cr);

  auto axcopy = [&](float* dst, const float* src, long long n, float s) {
    long long n4 = n / 4;
    long long b = (n4 + 255) / 256;
    int blocks = (int)(b < 2048 ? b : 2048);
    axcopy_kernel<<<blocks, 256, 0, stream>>>(dst, src, n4, s);
  };

  bool packable = (Ncg <= 131072) && (Nkg <= 131072) &&
                  (NBcg <= 256) && (NBkg <= 256) &&
                  (Ecg % 2 == 0) && (Ekg % 2 == 0);
  if (need * 4 > ws_size || !packable) {
    // -------- fallback: atomic push path (correct for any shape) --------
    float* buf0 = (float*)d_ws;
    float* buf1 = buf0 + Ncg * D;
    float* acck = buf1 + Ncg * D;
    auto spmm = [&](const int* r, const int* c, const float* v, const float* f,
                    float* o, long long ne) {
      long long threads = ne * 16;
      int blocks = (int)((threads + 255) / 256);
      spmm_atomic_kernel<<<blocks, 256, 0, stream>>>(r, c, v, f, o, ne);
    };
    auto normacc = [&](const float* f, float* a, long long nrows) {
      int blocks = (int)((nrows + 3) / 4);
      norm_acc_kernel<<<blocks, 256, 0, stream>>>(f, a, (int)nrows);
    };
    axcopy(buf0, learners, Lr * D, 1.f);
    axcopy(buf0 + Lr * D, courses, Cr * D, 1.f);
    axcopy(out, learners, Lr * D, 2.f);
    axcopy(out + Lr * D, courses, Cr * D, 1.f);
    hipMemsetAsync(buf1, 0, (size_t)(Ncg * D) * sizeof(float), stream);
    spmm(cg_rows, cg_cols, cg_vals, buf0, buf1, Ecg);
    normacc(buf1, out, Ncg);
    hipMemsetAsync(buf0, 0, (size_t)(Ncg * D) * sizeof(float), stream);
    spmm(cg_rows, cg_cols, cg_vals, buf1, buf0, Ecg);
    normacc(buf0, out, Ncg);
    axcopy(buf0, learners, Lr * D, 1.f);
    axcopy(buf0 + Lr * D, concepts, Kr * D, 1.f);
    axcopy(acck, concepts, Kr * D, 1.f);
    hipMemsetAsync(buf1, 0, (size_t)(Nkg * D) * sizeof(float), stream);
    spmm(kg_rows, kg_cols, kg_vals, buf0, buf1, Ekg);
    normacc(buf1, out, Lr);
    normacc(buf1 + Lr * D, acck, Kr);
    hipMemsetAsync(buf0, 0, (size_t)(Nkg * D) * sizeof(float), stream);
    spmm(kg_rows, kg_cols, kg_vals, buf1, buf0, Ekg);
    normacc(buf0, out, Lr);
    normacc(buf0 + Lr * D, acck, Kr);
    spmm(ca_rows, ca_cols, ca_vals, acck, out + Lr * D, Eca);
    return;
  }

  int*            binned = wsbase + o_share;
  unsigned short* g1     = (unsigned short*)(wsbase + o_share);  // disjoint lifetime
  unsigned short* g0     = (unsigned short*)(wsbase + o_g0);
  float* acck   = (float*)(wsbase + o_acck);
  int*   rp0    = wsbase + o_rp0;
  int*   rp1    = wsbase + o_rp1;
  int*   rp2    = wsbase + o_rp2;
  int*   cv0    = wsbase + o_cv0;
  int*   cv1    = wsbase + o_cv1;
  int*   cv2    = wsbase + o_cv2;
  int*   bkt    = wsbase + o_bkt;
  int*   cadeg  = wsbase + o_cadeg;
  float* scal   = (float*)(wsbase + o_scal);
  int*   part   = wsbase + o_part;
  int*   cacur  = wsbase + o_cacur;

  // ---- build ----
  hipMemsetAsync(bkt, 0, (size_t)(BKT_WORDS + ((Cr + 3) & ~3LL)) * sizeof(int), stream);
  bincnt_kernel<<<512, 1024, 0, stream>>>(cg_rows, cg_cols, EcgH, kg_rows, kg_cols, EkgH,
                                          ca_rows, Eca, bkt, cadeg,
                                          (int)Lr, NB0, s1cg, s1kg);
  bktscan_kernel<<<1, 256, 0, stream>>>(bkt, NBcg, NBkg);

  const int nbca = (int)((Cr + 1023) / 1024);
  ca_scan1_kernel<<<nbca, 256, 0, stream>>>(cadeg, rp2, scal + Ncg + Nkg, part, (int)Cr);
  ca_scan2_kernel<<<1, 256, 0, stream>>>(part, nbca);
  ca_scan3_kernel<<<nbca, 256, 0, stream>>>(rp2, part, cacur, (int)Cr, (int)Eca);

  {
    int blocks = (int)((EcgH + 256 * BCHUNK - 1) / (256 * BCHUNK));
    bin_kernel<<<blocks, 256, 0, stream>>>(cg_rows, cg_cols, EcgH, (int)Lr, s1cg, NB0, NBcg,
                                           bkt + BKT_CURCG, binned);
    fine2_kernel<<<NBcg, 1024, 0, stream>>>(binned, bkt + BKT_BASECG, rp0, cv0, scal,
                                            learners, courses, g0,
                                            (int)Lr, (int)Ncg, s1cg, NB0, (int)Ncg);
  }
  {
    int blocks = (int)((EkgH + 256 * BCHUNK - 1) / (256 * BCHUNK));
    bin_kernel<<<blocks, 256, 0, stream>>>(kg_rows, kg_cols, EkgH, (int)Lr, s1kg, NB0, NBkg,
                                           bkt + BKT_CURKG, binned);
    fine2_kernel<<<NBkg, 1024, 0, stream>>>(binned, bkt + BKT_BASEKG, rp1, cv1, scal + Ncg,
                                            learners, concepts, g0 + (long long)Ncg * D,
                                            (int)Lr, (int)Nkg, s1kg, NB0, (int)Nkg);
  }
  scatter_ca_kernel<<<(int)((Eca + 255) / 256), 256, 0, stream>>>(ca_rows, ca_cols, cacur, cv2, Eca);

  const unsigned short* g0cg = g0;
  const unsigned short* g0kg = g0 + (long long)Ncg * D;
  const float* sig_cg = scal;
  const float* sig_kg = scal + Ncg;
  const float* inv_ca = scal + Ncg + Nkg;

  // ---- course-grained view ----
  {
    int blocks = (int)((Ncg + 3) / 4);
    pull4_kernel<0, 1, 1><<<blocks, 256, 0, stream>>>(
        rp0, cv0, g0cg, g1, sig_cg,
        out, out, (int)Ncg,
        learners, courses, (int)Lr, 2.0f, 1.0f, (int)Ncg);
    pull4_kernel<1, 0, 0><<<blocks, 256, 0, stream>>>(
        rp0, cv0, g1, nullptr, nullptr,
        out, out, (int)Ncg,
        nullptr, nullptr, 0, 0.f, 0.f, (int)Ncg);
  }

  // ---- concept-grained view ----
  {
    int blocks = (int)((Nkg + 3) / 4);
    pull4_kernel<0, 0, 1><<<blocks, 256, 0, stream>>>(
        rp1, cv1, g0kg, g1, sig_kg,
        out, acck, (int)Lr,
        nullptr, concepts, (int)Lr, 0.f, 1.0f, (int)Nkg);
    pull4_kernel<1, 0, 0><<<blocks, 256, 0, stream>>>(
        rp1, cv1, g1, nullptr, nullptr,
        out, acck, (int)Lr,
        nullptr, nullptr, 0, 0.f, 0.f, (int)Nkg);
  }

  // ---- aggregate concept features into course rows ----
  {
    int blocks = (int)((Cr + 3) / 4);
    pull_ca_kernel<<<blocks, 256, 0, stream>>>(rp2, cv2, inv_ca, acck,
                                               out + Lr * D, (int)Cr);
  }
}

// Round 13
// 615.789 us; speedup vs baseline: 1.1668x; 1.0806x over previous
//
#include <hip/hip_runtime.h>

#define D 64
#define S0 10           // learner-side bucket shift (1024 rows/bucket)
#define BCHUNK 8        // edges per thread in bin pass
#define EPB (256 * BCHUNK)

// bkt[] layout (ints)
#define BKT_CNTCG 0
#define BKT_CNTKG 256
#define BKT_BASECG 512
#define BKT_BASEKG 772
#define BKT_CURCG 1032
#define BKT_CURKG 1288
#define BKT_WORDS 2048

__device__ __forceinline__ unsigned int f2bf(float x) {
  unsigned int u = __float_as_uint(x);
  return (u + 0x7FFFu + ((u >> 16) & 1u)) >> 16;
}

// ============================ element-wise utils (fallback only) ============================

__global__ __launch_bounds__(256) void axcopy_kernel(float* __restrict__ dst,
                                                     const float* __restrict__ src,
                                                     long long n4, float s) {
  long long i = (long long)blockIdx.x * blockDim.x + threadIdx.x;
  long long stride = (long long)gridDim.x * blockDim.x;
  for (; i < n4; i += stride) {
    float4 v = ((const float4*)src)[i];
    v.x *= s; v.y *= s; v.z *= s; v.w *= s;
    ((float4*)dst)[i] = v;
  }
}

// ============================ build ============================

// Pass A: bucket-occupancy counts in LDS (512 bins), one flush per block.
__global__ __launch_bounds__(1024) void bincnt_kernel(
    const int* __restrict__ cgr, const int* __restrict__ cgc, long long EcgH,
    const int* __restrict__ kgr, const int* __restrict__ kgc, long long EkgH,
    const int* __restrict__ car, long long Eca,
    int* __restrict__ bkt, int* __restrict__ cadeg,
    int L, int NB0, int s1cg, int s1kg) {
  __shared__ int h[512];
  int t = threadIdx.x;
  if (t < 512) h[t] = 0;
  __syncthreads();
  long long i = (long long)blockIdx.x * blockDim.x + t;
  long long stride = (long long)gridDim.x * blockDim.x;
  long long t01 = EcgH + EkgH, tot = t01 + Eca;
  for (; i < tot; i += stride) {
    if (i < EcgH) {
      int a = cgr[i], c = cgc[i];
      atomicAdd(&h[a >> S0], 1);
      atomicAdd(&h[NB0 + ((c - L) >> s1cg)], 1);
    } else if (i < t01) {
      long long j = i - EcgH;
      int a = kgr[j], c = kgc[j];
      atomicAdd(&h[256 + (a >> S0)], 1);
      atomicAdd(&h[256 + NB0 + ((c - L) >> s1kg)], 1);
    } else {
      long long j = i - t01;
      atomicAdd(&cadeg[car[j]], 1);
    }
  }
  __syncthreads();
  if (t < 512 && h[t]) atomicAdd(&bkt[t], h[t]);
}

// Exclusive scan of bucket counts -> local CSR bases; bin cursors (kg offset by Ecg
// so both graphs share one dense binned buffer in one bin dispatch).
__global__ __launch_bounds__(256) void bktscan_kernel(int* __restrict__ bkt,
                                                      int NBcg, int NBkg, int ecg) {
  __shared__ int lds[256];
  int t = threadIdx.x;
  #pragma unroll
  for (int g = 0; g < 2; ++g) {
    int NB      = g ? NBkg : NBcg;
    int cntoff  = g ? BKT_CNTKG : BKT_CNTCG;
    int baseoff = g ? BKT_BASEKG : BKT_BASECG;
    int curoff  = g ? BKT_CURKG : BKT_CURCG;
    int coff    = g ? ecg : 0;
    lds[t] = (t < NB) ? bkt[cntoff + t] : 0;
    __syncthreads();
    for (int off = 1; off < 256; off <<= 1) {
      int x = (t >= off) ? lds[t - off] : 0;
      __syncthreads();
      lds[t] += x;
      __syncthreads();
    }
    int excl = (t == 0) ? 0 : lds[t - 1];
    if (t < NB) { bkt[baseoff + t] = excl; bkt[curoff + t] = excl + coff; }
    if (t == NB - 1) bkt[baseoff + NB] = lds[t];
    __syncthreads();
  }
}

__global__ __launch_bounds__(256) void ca_scan1_kernel(const int* __restrict__ deg,
                                                       int* __restrict__ rp,
                                                       float* __restrict__ scal,
                                                       int* __restrict__ part, int n) {
  __shared__ int lds[256];
  int b = blockIdx.x, t = threadIdx.x;
  int base = b * 1024 + t * 4;
  int v[4]; int s = 0;
  #pragma unroll
  for (int j = 0; j < 4; j++) {
    int idx = base + j;
    v[j] = (idx < n) ? deg[idx] : 0;
    if (idx < n) scal[idx] = 1.0f / ((float)v[j] + 1e-8f);
    s += v[j];
  }
  lds[t] = s;
  __syncthreads();
  for (int off = 1; off < 256; off <<= 1) {
    int x = (t >= off) ? lds[t - off] : 0;
    __syncthreads();
    lds[t] += x;
    __syncthreads();
  }
  int run = (t == 0) ? 0 : lds[t - 1];
  if (t == 255) part[b] = lds[255];
  #pragma unroll
  for (int j = 0; j < 4; j++) { int idx = base + j; if (idx < n) rp[idx] = run; run += v[j]; }
}

__global__ __launch_bounds__(256) void ca_scan2_kernel(int* __restrict__ part, int nb) {
  __shared__ int lds[256];
  int t = threadIdx.x;
  lds[t] = (t < nb) ? part[t] : 0;
  __syncthreads();
  for (int off = 1; off < 256; off <<= 1) {
    int x = (t >= off) ? lds[t - off] : 0;
    __syncthreads();
    lds[t] += x;
    __syncthreads();
  }
  if (t < nb) part[t] = (t == 0) ? 0 : lds[t - 1];
}

__global__ __launch_bounds__(256) void ca_scan3_kernel(int* __restrict__ rp,
                                                       const int* __restrict__ part,
                                                       int* __restrict__ cacur,
                                                       int n, int total) {
  int b = blockIdx.x, t = threadIdx.x;
  int add = part[b];
  int base = b * 1024 + t * 4;
  #pragma unroll
  for (int j = 0; j < 4; j++) {
    int idx = base + j;
    if (idx < n) { int f = rp[idx] + add; rp[idx] = f; cacur[idx] = f; }
  }
  if (b == 0 && t == 0) rp[n] = total;
}

// Merged bin pass: cg blocks | kg blocks, one dispatch (better CU fill).
// Dense regions; kg cursors pre-offset by Ecg (bktscan).
__global__ __launch_bounds__(256) void bin_all_kernel(
    const int* __restrict__ cgr, const int* __restrict__ cgc, long long EcgH, int Bcg,
    const int* __restrict__ kgr, const int* __restrict__ kgc, long long EkgH,
    int L, int s1cg, int s1kg, int NB0, int NBcg, int NBkg,
    int* __restrict__ bkt, int* __restrict__ binned) {
  int B = blockIdx.x;
  int t = threadIdx.x;
  const int* rowsA; const int* colsA; long long E; int s1, NBtot; int* gcur; long long eb;
  if (B < Bcg) { rowsA = cgr; colsA = cgc; E = EcgH; s1 = s1cg; NBtot = NBcg; gcur = bkt + BKT_CURCG; eb = (long long)B * EPB; }
  else         { rowsA = kgr; colsA = kgc; E = EkgH; s1 = s1kg; NBtot = NBkg; gcur = bkt + BKT_CURKG; eb = (long long)(B - Bcg) * EPB; }

  __shared__ int cnt[256];
  __shared__ int gbase[256];
  cnt[t] = 0;
  __syncthreads();
  int av[BCHUNK], cv_[BCHUNK], l0[BCHUNK], l1[BCHUNK];
  #pragma unroll
  for (int k = 0; k < BCHUNK; k++) {
    long long i = eb + (long long)k * 256 + t;
    bool ok = i < E;
    int a = ok ? rowsA[i] : 0;
    int c = ok ? colsA[i] : L;
    av[k] = a; cv_[k] = c;
    if (ok) {
      int b0 = a >> S0;
      int b1 = NB0 + ((c - L) >> s1);
      l0[k] = atomicAdd(&cnt[b0], 1);
      l1[k] = atomicAdd(&cnt[b1], 1);
    } else { l0[k] = 0; l1[k] = 0; }
  }
  __syncthreads();
  if (t < NBtot) gbase[t] = cnt[t] ? atomicAdd(&gcur[t], cnt[t]) : 0;
  __syncthreads();
  #pragma unroll
  for (int k = 0; k < BCHUNK; k++) {
    long long i = eb + (long long)k * 256 + t;
    if (i < E) {
      int a = av[k], c = cv_[k];
      int b0 = a >> S0;
      int b1 = NB0 + ((c - L) >> s1);
      binned[gbase[b0] + l0[k]] = ((a & ((1 << S0) - 1)) << 17) | c;
      binned[gbase[b1] + l1[k]] = (((c - L) & ((1 << s1) - 1)) << 17) | a;
    }
  }
}

// Per-bucket finalize, one graph per dispatch (concurrent scatter windows <= L2).
// Count rows in LDS, wave-shfl scan, write rp/sigma, coalesced fused bf16 g0
// conversion, scatter via LDS cursors.
__global__ __launch_bounds__(1024) void fine2_kernel(
    const int* __restrict__ binned, const int* __restrict__ bktbase,
    int* __restrict__ rp, int* __restrict__ cvout, float* __restrict__ scal,
    const float* __restrict__ fA, const float* __restrict__ fB,
    unsigned short* __restrict__ g0g,
    int L, int sideEnd, int s1, int NB0, int nfull) {
  __shared__ int cnt[1 << S0];
  __shared__ int wsum[16];
  int b = blockIdx.x, t = threadIdx.x;
  int rowbase, rowend;
  if (b < NB0) { rowbase = b << S0; rowend = min(rowbase + (1 << S0), L); }
  else { int bb = b - NB0; rowbase = L + (bb << s1); rowend = min(rowbase + (1 << s1), sideEnd); }
  int nrows = rowend - rowbase;
  int base = bktbase[b], end = bktbase[b + 1];
  cnt[t] = 0;
  __syncthreads();
  for (int i = base + t; i < end; i += 1024) atomicAdd(&cnt[binned[i] >> 17], 1);
  __syncthreads();
  int deg = cnt[t];
  int lane = t & 63, wid = t >> 6;
  int v = deg;
  #pragma unroll
  for (int off = 1; off < 64; off <<= 1) {
    int y = __shfl_up(v, off);
    if (lane >= off) v += y;
  }
  if (lane == 63) wsum[wid] = v;
  __syncthreads();
  if (t == 0) { int run = 0; for (int w = 0; w < 16; w++) { int x = wsum[w]; wsum[w] = run; run += x; } }
  __syncthreads();
  int pos = base + wsum[wid] + (v - deg);
  cnt[t] = pos;            // reuse as row cursor
  if (t < nrows) {
    rp[rowbase + t] = pos;
    scal[rowbase + t] = 1.0f / (sqrtf((float)deg) + 1e-8f);
  }
  if (b == gridDim.x - 1 && t == 0) rp[nfull] = end;
  __syncthreads();

  // fused coalesced g0 conversion: each wave converts 4 rows/iter (16 lanes/row)
  for (int r0 = wid * 4 + (lane >> 4); r0 < nrows; r0 += 64) {
    int row = rowbase + r0;
    float sg = scal[row];
    int sub = lane & 15;
    const float* src = (row < L ? fA + (long long)row * D
                                : fB + (long long)(row - L) * D) + sub * 4;
    float4 x = *(const float4*)src;
    unsigned int lo = f2bf(x.x * sg) | (f2bf(x.y * sg) << 16);
    unsigned int hi = f2bf(x.z * sg) | (f2bf(x.w * sg) << 16);
    *(uint2*)(g0g + (long long)row * D + sub * 4) = make_uint2(lo, hi);
  }

  for (int i = base + t; i < end; i += 1024) {
    int w = binned[i];
    int p = atomicAdd(&cnt[w >> 17], 1);
    cvout[p] = w & 0x1FFFF;
  }
}

__global__ __launch_bounds__(256) void scatter_ca_kernel(
    const int* __restrict__ rows, const int* __restrict__ cols,
    int* __restrict__ rowcur, int* __restrict__ cv, long long ne) {
  long long e = (long long)blockIdx.x * blockDim.x + threadIdx.x;
  if (e >= ne) return;
  int p = atomicAdd(&rowcur[rows[e]], 1);
  cv[p] = cols[e];
}

// ============================ merged pull SpMM ============================
// 16-edge MLP bf16 gather with 32-bit saddr offsets.
__device__ __forceinline__ void gather16(
    const int* __restrict__ rowptr, const int* __restrict__ cols,
    const unsigned short* __restrict__ gt, int row, int grp, unsigned int dimoff,
    float& sx, float& sy, float& sz, float& sw) {
  int e0 = rowptr[row], e1 = rowptr[row + 1];
  int e = e0;
  for (; e + 16 <= e1; e += 16) {
    int c0 = cols[e + grp];
    int c1 = cols[e + 4 + grp];
    int c2 = cols[e + 8 + grp];
    int c3 = cols[e + 12 + grp];
    uint2 v0 = *(const uint2*)((const char*)gt + (((unsigned int)c0 << 7) + dimoff));
    uint2 v1 = *(const uint2*)((const char*)gt + (((unsigned int)c1 << 7) + dimoff));
    uint2 v2 = *(const uint2*)((const char*)gt + (((unsigned int)c2 << 7) + dimoff));
    uint2 v3 = *(const uint2*)((const char*)gt + (((unsigned int)c3 << 7) + dimoff));
    sx += __uint_as_float(v0.x << 16);
    sy += __uint_as_float(v0.x & 0xFFFF0000u);
    sz += __uint_as_float(v0.y << 16);
    sw += __uint_as_float(v0.y & 0xFFFF0000u);
    sx += __uint_as_float(v1.x << 16);
    sy += __uint_as_float(v1.x & 0xFFFF0000u);
    sz += __uint_as_float(v1.y << 16);
    sw += __uint_as_float(v1.y & 0xFFFF0000u);
    sx += __uint_as_float(v2.x << 16);
    sy += __uint_as_float(v2.x & 0xFFFF0000u);
    sz += __uint_as_float(v2.y << 16);
    sw += __uint_as_float(v2.y & 0xFFFF0000u);
    sx += __uint_as_float(v3.x << 16);
    sy += __uint_as_float(v3.x & 0xFFFF0000u);
    sz += __uint_as_float(v3.y << 16);
    sw += __uint_as_float(v3.y & 0xFFFF0000u);
  }
  for (int ee = e + grp; ee < e1; ee += 4) {
    int c = cols[ee];
    uint2 v = *(const uint2*)((const char*)gt + (((unsigned int)c << 7) + dimoff));
    sx += __uint_as_float(v.x << 16);
    sy += __uint_as_float(v.x & 0xFFFF0000u);
    sz += __uint_as_float(v.y << 16);
    sw += __uint_as_float(v.y & 0xFFFF0000u);
  }
}

// One wave per OUTPUT row; learner rows process BOTH views (no out RMW race,
// single out write per layer). MODE 0 = layer 1 (init bases, write g1),
// MODE 1 = layer 2 (accumulate, no g1).
template <int MODE>
__global__ __launch_bounds__(256) void pull_merged_kernel(
    const int* __restrict__ rp0, const int* __restrict__ cv0,
    const unsigned short* __restrict__ gtc,
    const int* __restrict__ rp1, const int* __restrict__ cv1,
    const unsigned short* __restrict__ gtk,
    unsigned short* __restrict__ g1c, unsigned short* __restrict__ g1k,
    const float* __restrict__ sigc, const float* __restrict__ sigk,
    float* __restrict__ outp, float* __restrict__ acck,
    const float* __restrict__ learners, const float* __restrict__ courses,
    const float* __restrict__ concepts,
    int Lr, int Cr, int Kr) {
  int u = blockIdx.x * 4 + (threadIdx.x >> 6);
  int ntot = Lr + Cr + Kr;
  if (u >= ntot) return;
  int lane = threadIdx.x & 63;
  int sub = lane & 15;
  int grp = lane >> 4;
  unsigned int dimoff = (unsigned int)(sub << 3);
  bool hasCg = u < Lr + Cr;
  bool hasKg = (u < Lr) || (u >= Lr + Cr);
  int kgrow = (u < Lr) ? u : u - Cr;

  float ax = 0, ay = 0, az = 0, aw = 0;
  float bx = 0, by = 0, bz = 0, bw = 0;
  if (hasCg) gather16(rp0, cv0, gtc, u, grp, dimoff, ax, ay, az, aw);
  if (hasKg) gather16(rp1, cv1, gtk, kgrow, grp, dimoff, bx, by, bz, bw);

  #pragma unroll
  for (int off = 16; off <= 32; off <<= 1) {
    ax += __shfl_xor(ax, off); ay += __shfl_xor(ay, off);
    az += __shfl_xor(az, off); aw += __shfl_xor(aw, off);
    bx += __shfl_xor(bx, off); by += __shfl_xor(by, off);
    bz += __shfl_xor(bz, off); bw += __shfl_xor(bw, off);
  }
  float q1 = ax * ax + ay * ay + az * az + aw * aw;
  float q2 = bx * bx + by * by + bz * bz + bw * bw;
  #pragma unroll
  for (int off = 1; off <= 8; off <<= 1) {
    q1 += __shfl_xor(q1, off);
    q2 += __shfl_xor(q2, off);
  }
  float r1 = 1.0f / fmaxf(sqrtf(q1), 1e-12f);
  float r2 = 1.0f / fmaxf(sqrtf(q2), 1e-12f);

  if (grp == 0) {
    long long o4 = (long long)(sub << 2);
    if (MODE == 0) {
      if (hasCg) {
        float f = sigc[u]; f *= f;
        unsigned int lo = f2bf(f * ax) | (f2bf(f * ay) << 16);
        unsigned int hi = f2bf(f * az) | (f2bf(f * aw) << 16);
        *(uint2*)(g1c + ((long long)u << 6) + (sub << 2)) = make_uint2(lo, hi);
      }
      if (hasKg) {
        float f = sigk[kgrow]; f *= f;
        unsigned int lo = f2bf(f * bx) | (f2bf(f * by) << 16);
        unsigned int hi = f2bf(f * bz) | (f2bf(f * bw) << 16);
        *(uint2*)(g1k + ((long long)kgrow << 6) + (sub << 2)) = make_uint2(lo, hi);
      }
    }
    if (u < Lr) {
      float* dst = outp + ((long long)u << 6);
      float4 base;
      if (MODE == 0) {
        float4 v = *(const float4*)(learners + ((long long)u << 6) + o4);
        base = make_float4(2.f * v.x, 2.f * v.y, 2.f * v.z, 2.f * v.w);
      } else base = *(const float4*)(dst + o4);
      *(float4*)(dst + o4) = make_float4(base.x + ax * r1 + bx * r2,
                                         base.y + ay * r1 + by * r2,
                                         base.z + az * r1 + bz * r2,
                                         base.w + aw * r1 + bw * r2);
    } else if (u < Lr + Cr) {
      float* dst = outp + ((long long)u << 6);
      float4 base;
      if (MODE == 0) base = *(const float4*)(courses + ((long long)(u - Lr) << 6) + o4);
      else base = *(const float4*)(dst + o4);
      *(float4*)(dst + o4) = make_float4(base.x + ax * r1, base.y + ay * r1,
                                         base.z + az * r1, base.w + aw * r1);
    } else {
      int k = u - Lr - Cr;
      float* dst = acck + ((long long)k << 6);
      float4 base;
      if (MODE == 0) base = *(const float4*)(concepts + ((long long)k << 6) + o4);
      else base = *(const float4*)(dst + o4);
      *(float4*)(dst + o4) = make_float4(base.x + bx * r2, base.y + by * r2,
                                         base.z + bz * r2, base.w + bw * r2);
    }
  }
}

__global__ __launch_bounds__(256) void pull_ca_kernel(
    const int* __restrict__ rowptr, const int* __restrict__ cols,
    const float* __restrict__ invdeg, const float* __restrict__ feat,
    float* __restrict__ acc, int nrows) {
  int row = blockIdx.x * 4 + (threadIdx.x >> 6);
  if (row >= nrows) return;
  int lane = threadIdx.x & 63;
  int e0 = rowptr[row], e1 = rowptr[row + 1];
  float s = 0.f;
  for (int e = e0; e < e1; ++e) s += feat[((long long)cols[e] << 6) + lane];
  acc[((long long)row << 6) + lane] += invdeg[row] * s;
}

// ============================ fallback (atomic push path) ============================

__global__ __launch_bounds__(256) void spmm_atomic_kernel(
    const int* __restrict__ rows, const int* __restrict__ cols,
    const float* __restrict__ vals, const float* __restrict__ feat,
    float* __restrict__ outp, long long ne) {
  long long t = (long long)blockIdx.x * blockDim.x + threadIdx.x;
  long long e = t >> 4;
  if (e >= ne) return;
  int lane = (int)(t & 15);
  int r = rows[e];
  int c = cols[e];
  float v = vals[e];
  const float4 f = *(const float4*)(feat + (long long)c * D + lane * 4);
  float* o = outp + (long long)r * D + lane * 4;
  atomicAdd(o + 0, v * f.x);
  atomicAdd(o + 1, v * f.y);
  atomicAdd(o + 2, v * f.z);
  atomicAdd(o + 3, v * f.w);
}

__global__ __launch_bounds__(256) void norm_acc_kernel(const float* __restrict__ feat,
                                                       float* __restrict__ acc,
                                                       int nrows) {
  int row = blockIdx.x * 4 + (threadIdx.x >> 6);
  if (row >= nrows) return;
  int lane = threadIdx.x & 63;
  float x = feat[(long long)row * D + lane];
  float s = x * x;
  #pragma unroll
  for (int off = 32; off; off >>= 1) s += __shfl_xor(s, off);
  float sc = 1.0f / fmaxf(sqrtf(s), 1e-12f);
  acc[(long long)row * D + lane] += x * sc;
}

// ============================ launch ============================

extern "C" void kernel_launch(void* const* d_in, const int* in_sizes, int n_in,
                              void* d_out, int out_size, void* d_ws, size_t ws_size,
                              hipStream_t stream) {
  const float* learners = (const float*)d_in[0];
  const float* courses  = (const float*)d_in[1];
  const float* concepts = (const float*)d_in[2];
  const int*   cg_rows  = (const int*)d_in[3];
  const int*   cg_cols  = (const int*)d_in[4];
  const int*   kg_rows  = (const int*)d_in[6];
  const int*   kg_cols  = (const int*)d_in[7];
  const int*   ca_rows  = (const int*)d_in[9];
  const int*   ca_cols  = (const int*)d_in[10];
  const float* cg_vals  = (const float*)d_in[5];
  const float* kg_vals  = (const float*)d_in[8];
  const float* ca_vals  = (const float*)d_in[11];

  const long long Lr  = in_sizes[0] / D;
  const long long Cr  = in_sizes[1] / D;
  const long long Kr  = in_sizes[2] / D;
  const long long Ecg = in_sizes[3];
  const long long Ekg = in_sizes[6];
  const long long Eca = in_sizes[9];
  const long long EcgH = Ecg / 2;
  const long long EkgH = Ekg / 2;
  const long long Ncg = Lr + Cr;
  const long long Nkg = Lr + Kr;

  float* out = (float*)d_out;

  const int NB0   = (int)((Lr + (1 << S0) - 1) >> S0);
  const int s1cg  = 8;
  const int s1kg  = 6;
  const int NBcg  = NB0 + (int)((Cr + (1 << s1cg) - 1) >> s1cg);
  const int NBkg  = NB0 + (int)((Kr + (1 << s1kg) - 1) >> s1kg);

  // ---- workspace layout (words) ----
  long long g1W = (Ncg + Nkg) * 32;                       // both views' g1 (bf16)
  long long binW = Ecg + Ekg;                             // merged dense binned
  long long shareW = binW > g1W ? binW : g1W;
  size_t need = 0;
  auto walloc = [&](long long elems) { size_t off = need; need += ((size_t)elems + 3) & ~(size_t)3; return off; };
  int* wsbase = (int*)d_ws;
  size_t o_share = walloc(shareW);                  // binned scratch, then g1 (cg|kg)
  size_t o_g0    = walloc((Ncg + Nkg) * 32);        // bf16 sigma-scaled feat0 tables
  size_t o_acck  = walloc(Kr * D);
  size_t o_rp0   = walloc(Ncg + 1);
  size_t o_rp1   = walloc(Nkg + 1);
  size_t o_rp2   = walloc(Cr + 1);
  size_t o_cv0   = walloc(Ecg);
  size_t o_cv1   = walloc(Ekg);
  size_t o_cv2   = walloc(Eca);
  size_t o_bkt   = walloc(BKT_WORDS);
  size_t o_cadeg = walloc(Cr);
  size_t o_scal  = walloc(Ncg + Nkg + Cr);
  size_t o_part  = walloc(512);
  size_t o_cacur = walloc(Cr);

  auto axcopy = [&](float* dst, const float* src, long long n, float s) {
    long long n4 = n / 4;
    long long b = (n4 + 255) / 256;
    int blocks = (int)(b < 2048 ? b : 2048);
    axcopy_kernel<<<blocks, 256, 0, stream>>>(dst, src, n4, s);
  };

  bool packable = (Ncg <= 131072) && (Nkg <= 131072) &&
                  (NBcg <= 256) && (NBkg <= 256) &&
                  (Ecg % 2 == 0) && (Ekg % 2 == 0);
  if (need * 4 > ws_size || !packable) {
    // -------- fallback: atomic push path (correct for any shape) --------
    float* buf0 = (float*)d_ws;
    float* buf1 = buf0 + Ncg * D;
    float* acck = buf1 + Ncg * D;
    auto spmm = [&](const int* r, const int* c, const float* v, const float* f,
                    float* o, long long ne) {
      long long threads = ne * 16;
      int blocks = (int)((threads + 255) / 256);
      spmm_atomic_kernel<<<blocks, 256, 0, stream>>>(r, c, v, f, o, ne);
    };
    auto normacc = [&](const float* f, float* a, long long nrows) {
      int blocks = (int)((nrows + 3) / 4);
      norm_acc_kernel<<<blocks, 256, 0, stream>>>(f, a, (int)nrows);
    };
    axcopy(buf0, learners, Lr * D, 1.f);
    axcopy(buf0 + Lr * D, courses, Cr * D, 1.f);
    axcopy(out, learners, Lr * D, 2.f);
    axcopy(out + Lr * D, courses, Cr * D, 1.f);
    hipMemsetAsync(buf1, 0, (size_t)(Ncg * D) * sizeof(float), stream);
    spmm(cg_rows, cg_cols, cg_vals, buf0, buf1, Ecg);
    normacc(buf1, out, Ncg);
    hipMemsetAsync(buf0, 0, (size_t)(Ncg * D) * sizeof(float), stream);
    spmm(cg_rows, cg_cols, cg_vals, buf1, buf0, Ecg);
    normacc(buf0, out, Ncg);
    axcopy(buf0, learners, Lr * D, 1.f);
    axcopy(buf0 + Lr * D, concepts, Kr * D, 1.f);
    axcopy(acck, concepts, Kr * D, 1.f);
    hipMemsetAsync(buf1, 0, (size_t)(Nkg * D) * sizeof(float), stream);
    spmm(kg_rows, kg_cols, kg_vals, buf0, buf1, Ekg);
    normacc(buf1, out, Lr);
    normacc(buf1 + Lr * D, acck, Kr);
    hipMemsetAsync(buf0, 0, (size_t)(Nkg * D) * sizeof(float), stream);
    spmm(kg_rows, kg_cols, kg_vals, buf1, buf0, Ekg);
    normacc(buf0, out, Lr);
    normacc(buf0 + Lr * D, acck, Kr);
    spmm(ca_rows, ca_cols, ca_vals, acck, out + Lr * D, Eca);
    return;
  }

  int*            binned = wsbase + o_share;
  unsigned short* g1c    = (unsigned short*)(wsbase + o_share);  // disjoint lifetime
  unsigned short* g1k    = g1c + (long long)Ncg * D;
  unsigned short* g0     = (unsigned short*)(wsbase + o_g0);
  float* acck   = (float*)(wsbase + o_acck);
  int*   rp0    = wsbase + o_rp0;
  int*   rp1    = wsbase + o_rp1;
  int*   rp2    = wsbase + o_rp2;
  int*   cv0    = wsbase + o_cv0;
  int*   cv1    = wsbase + o_cv1;
  int*   cv2    = wsbase + o_cv2;
  int*   bkt    = wsbase + o_bkt;
  int*   cadeg  = wsbase + o_cadeg;
  float* scal   = (float*)(wsbase + o_scal);
  int*   part   = wsbase + o_part;
  int*   cacur  = wsbase + o_cacur;

  // ---- build ----
  hipMemsetAsync(bkt, 0, (size_t)(BKT_WORDS + ((Cr + 3) & ~3LL)) * sizeof(int), stream);
  bincnt_kernel<<<512, 1024, 0, stream>>>(cg_rows, cg_cols, EcgH, kg_rows, kg_cols, EkgH,
                                          ca_rows, Eca, bkt, cadeg,
                                          (int)Lr, NB0, s1cg, s1kg);
  bktscan_kernel<<<1, 256, 0, stream>>>(bkt, NBcg, NBkg, (int)Ecg);

  const int nbca = (int)((Cr + 1023) / 1024);
  ca_scan1_kernel<<<nbca, 256, 0, stream>>>(cadeg, rp2, scal + Ncg + Nkg, part, (int)Cr);
  ca_scan2_kernel<<<1, 256, 0, stream>>>(part, nbca);
  ca_scan3_kernel<<<nbca, 256, 0, stream>>>(rp2, part, cacur, (int)Cr, (int)Eca);

  const int Bcg = (int)((EcgH + EPB - 1) / EPB);
  const int Bkg = (int)((EkgH + EPB - 1) / EPB);
  bin_all_kernel<<<Bcg + Bkg, 256, 0, stream>>>(cg_rows, cg_cols, EcgH, Bcg,
                                                kg_rows, kg_cols, EkgH,
                                                (int)Lr, s1cg, s1kg, NB0, NBcg, NBkg,
                                                bkt, binned);
  fine2_kernel<<<NBcg, 1024, 0, stream>>>(binned, bkt + BKT_BASECG, rp0, cv0, scal,
                                          learners, courses, g0,
                                          (int)Lr, (int)Ncg, s1cg, NB0, (int)Ncg);
  fine2_kernel<<<NBkg, 1024, 0, stream>>>(binned + Ecg, bkt + BKT_BASEKG, rp1, cv1, scal + Ncg,
                                          learners, concepts, g0 + (long long)Ncg * D,
                                          (int)Lr, (int)Nkg, s1kg, NB0, (int)Nkg);
  scatter_ca_kernel<<<(int)((Eca + 255) / 256), 256, 0, stream>>>(ca_rows, ca_cols, cacur, cv2, Eca);

  const unsigned short* g0cg = g0;
  const unsigned short* g0kg = g0 + (long long)Ncg * D;
  const float* sig_cg = scal;
  const float* sig_kg = scal + Ncg;
  const float* inv_ca = scal + Ncg + Nkg;

  // ---- merged pulls: L1 then L2 ----
  {
    int blocks = (int)((Lr + Cr + Kr + 3) / 4);
    pull_merged_kernel<0><<<blocks, 256, 0, stream>>>(
        rp0, cv0, g0cg, rp1, cv1, g0kg,
        g1c, g1k, sig_cg, sig_kg,
        out, acck, learners, courses, concepts,
        (int)Lr, (int)Cr, (int)Kr);
    pull_merged_kernel<1><<<blocks, 256, 0, stream>>>(
        rp0, cv0, g1c, rp1, cv1, g1k,
        nullptr, nullptr, nullptr, nullptr,
        out, acck, learners, courses, concepts,
        (int)Lr, (int)Cr, (int)Kr);
  }

  // ---- aggregate concept features into course rows ----
  {
    int blocks = (int)((Cr + 3) / 4);
    pull_ca_kernel<<<blocks, 256, 0, stream>>>(rp2, cv2, inv_ca, acck,
                                               out + Lr * D, (int)Cr);
  }
}